// Round 11
// baseline (1515.037 us; speedup 1.0000x reference)
//
#include <hip/hip_runtime.h>

#define Bc 4
#define Tc 500
#define Uc 100
#define Vc 64
#define G4 2048

typedef __attribute__((ext_vector_type(8))) short short8v;
typedef __attribute__((ext_vector_type(4))) float f32x4;
typedef _Float16 h2v __attribute__((ext_vector_type(2)));

#define SMEM_BYTES 124416
#define WL_WORDS_STRIDE 260      // 2-way bank conflict (free), 16B-aligned rows
#define HL_OFF 99840             // 96*260*4
#define RED_OFF 108032           // HL_OFF + 8192

__device__ __forceinline__ float fsig(float x) {
  return __builtin_amdgcn_rcpf(1.f + __expf(-x));
}
__device__ __forceinline__ float ftanh(float x) {
  float e = __expf(2.f * x);
  return 1.f - 2.f * __builtin_amdgcn_rcpf(e + 1.f);
}
__device__ __forceinline__ short f2bf(float f) {
  unsigned u = __float_as_uint(f);
  unsigned r = (u + 0x7FFFu + ((u >> 16) & 1u)) >> 16;
  return (short)r;
}

__device__ __forceinline__ unsigned ldA(const unsigned* p) {
  return __hip_atomic_load(p, __ATOMIC_RELAXED, __HIP_MEMORY_SCOPE_AGENT);
}
__device__ __forceinline__ void stA(unsigned* p, unsigned v) {
  __hip_atomic_store(p, v, __ATOMIC_RELAXED, __HIP_MEMORY_SCOPE_AGENT);
}

// ---------------- generic GEMM tile (uses carved smem) ----------------
template <int ATOMICST>
__device__ __forceinline__ void gemm_tile(
    char* smem,
    const float* __restrict__ A, int lda,
    const float* __restrict__ Bw, int ldb,
    const float* __restrict__ bias, const float* __restrict__ bias2,
    float* __restrict__ C, int ldc, int N, int m0, int n0,
    const int* __restrict__ ids, const float* __restrict__ emb)
{
  float (*As)[65] = (float (*)[65])smem;
  float (*Bs)[65] = (float (*)[65])(smem + 4160);
  const int tid = threadIdx.x;
  const int tx = tid & 15, ty = tid >> 4;
  float acc[4][4] = {};
  for (int k0 = 0; k0 < 512; k0 += 16) {
#pragma unroll
    for (int i = 0; i < 4; ++i) {
      int n = n0 + ty + 16 * i;
      float av = 0.f;
      if (n < N) {
        const float* ar = ids ? (emb + (long)ids[n] * 512) : (A + (long)n * lda);
        av = ar[k0 + tx];
      }
      As[tx][ty + 16 * i] = av;
      Bs[tx][ty + 16 * i] = Bw[(long)(m0 + ty + 16 * i) * ldb + k0 + tx];
    }
    __syncthreads();
#pragma unroll
    for (int kl = 0; kl < 16; ++kl) {
      float a[4], b[4];
#pragma unroll
      for (int i = 0; i < 4; ++i) a[i] = As[kl][ty * 4 + i];
#pragma unroll
      for (int j = 0; j < 4; ++j) b[j] = Bs[kl][tx * 4 + j];
#pragma unroll
      for (int i = 0; i < 4; ++i)
#pragma unroll
        for (int j = 0; j < 4; ++j) acc[i][j] += a[i] * b[j];
    }
    __syncthreads();
  }
#pragma unroll
  for (int i = 0; i < 4; ++i) {
    int n = n0 + ty * 4 + i;
    if (n >= N) continue;
#pragma unroll
    for (int j = 0; j < 4; ++j) {
      int m = m0 + tx * 4 + j;
      float v = acc[i][j];
      if (bias)  v += bias[m];
      if (bias2) v += bias2[m];
      if (ATOMICST)
        stA((unsigned*)C + (long)n * ldc + m, __float_as_uint(v));
      else
        C[(long)n * ldc + m] = v;
    }
  }
}

// ---------------- wdc tile: wdc[h][e] = sum_d wd[h][d]*fc_w[d][e] ----------------
__device__ void wdc_tile(char* smem,
                         const float* __restrict__ jw1,
                         const float* __restrict__ fc_w,
                         float* __restrict__ wdc, int n0, int m0)
{
  float (*As)[65] = (float (*)[65])smem;
  float (*Bs)[65] = (float (*)[65])(smem + 4160);
  const int tid = threadIdx.x;
  const int tx = tid & 15, ty = tid >> 4;
  float acc[4][4] = {};
  for (int k0 = 0; k0 < 512; k0 += 16) {
#pragma unroll
    for (int i = 0; i < 4; ++i) {
      As[tx][ty + 16 * i] = jw1[(long)(n0 + ty + 16 * i) * 1024 + 512 + k0 + tx];
      Bs[ty][tx + 16 * i] = fc_w[(long)(k0 + ty) * 512 + m0 + tx + 16 * i];
    }
    __syncthreads();
#pragma unroll
    for (int kl = 0; kl < 16; ++kl) {
      float a[4], b[4];
#pragma unroll
      for (int i = 0; i < 4; ++i) a[i] = As[kl][ty * 4 + i];
#pragma unroll
      for (int j = 0; j < 4; ++j) b[j] = Bs[kl][tx * 4 + j];
#pragma unroll
      for (int i = 0; i < 4; ++i)
#pragma unroll
        for (int j = 0; j < 4; ++j) acc[i][j] += a[i] * b[j];
    }
    __syncthreads();
  }
#pragma unroll
  for (int i = 0; i < 4; ++i)
#pragma unroll
    for (int j = 0; j < 4; ++j)
      stA((unsigned*)wdc + (long)(n0 + ty * 4 + i) * 512 + m0 + tx * 4 + j,
          __float_as_uint(acc[i][j]));
}

// ---------------- dec tile (advisory flag + per-word NaN backstop) ----------
__device__ void dec_tile(char* smem,
                         const float* __restrict__ h1s, const float* __restrict__ wdc,
                         const float* __restrict__ jw1, const float* __restrict__ fc_b,
                         const float* __restrict__ jb1, float* __restrict__ decb,
                         const int* __restrict__ f1, int m0, int n0)
{
  float (*As)[65] = (float (*)[65])smem;
  float (*Bs)[65] = (float (*)[65])(smem + 4160);
  float* biasl = (float*)(smem + 8320);
  const int tid = threadIdx.x;
  const int tx = tid & 15, ty = tid >> 4;
  int u_hi = 0;
  for (int rr = 0; rr < 64; ++rr) {
    int r = n0 + rr;
    if (r < 400) { int u = r % Uc; u_hi = max(u_hi, u + 1); }
  }
  if (tid < 16)   // 16 L1 blocks now
    while ((int)ldA((const unsigned*)(f1 + tid * 16)) < u_hi)
      __builtin_amdgcn_s_sleep(8);
  if (tid < 64) {
    int m = m0 + tid;
    const float4* wp = (const float4*)(jw1 + (long)m * 1024 + 512);
    const float4* fb = (const float4*)fc_b;
    float bb = jb1[m];
#pragma unroll 8
    for (int d4 = 0; d4 < 128; ++d4) {
      float4 w = wp[d4], f = fb[d4];
      bb += w.x * f.x + w.y * f.y + w.z * f.z + w.w * f.w;
    }
    biasl[tid] = bb;
  }
  __syncthreads();
  const unsigned* h1u = (const unsigned*)h1s;
  const unsigned* wdu = (const unsigned*)wdc;
  float acc[4][4] = {};
  for (int k0 = 0; k0 < 512; k0 += 16) {
    unsigned uA[4], uB[4];
#pragma unroll
    for (int i = 0; i < 4; ++i) {
      int n = n0 + ty + 16 * i;
      uA[i] = (n < 400) ? ldA(h1u + (long)(n % Uc) * G4 + (n / Uc) * 512 + k0 + tx) : 0u;
      uB[i] = ldA(wdu + (long)(m0 + ty + 16 * i) * 512 + k0 + tx);
    }
#pragma unroll
    for (int i = 0; i < 4; ++i) {
      int n = n0 + ty + 16 * i;
      while (uA[i] == 0xFFFFFFFFu)
        uA[i] = ldA(h1u + (long)(n % Uc) * G4 + (n / Uc) * 512 + k0 + tx);
      while (uB[i] == 0xFFFFFFFFu)
        uB[i] = ldA(wdu + (long)(m0 + ty + 16 * i) * 512 + k0 + tx);
      As[tx][ty + 16 * i] = __uint_as_float(uA[i]);
      Bs[tx][ty + 16 * i] = __uint_as_float(uB[i]);
    }
    __syncthreads();
#pragma unroll
    for (int kl = 0; kl < 16; ++kl) {
      float a[4], b[4];
#pragma unroll
      for (int i = 0; i < 4; ++i) a[i] = As[kl][ty * 4 + i];
#pragma unroll
      for (int j = 0; j < 4; ++j) b[j] = Bs[kl][tx * 4 + j];
#pragma unroll
      for (int i = 0; i < 4; ++i)
#pragma unroll
        for (int j = 0; j < 4; ++j) acc[i][j] += a[i] * b[j];
    }
    __syncthreads();
  }
#pragma unroll
  for (int i = 0; i < 4; ++i) {
    int n = n0 + ty * 4 + i;
    if (n >= 400) continue;
#pragma unroll
    for (int j = 0; j < 4; ++j)
      stA((unsigned*)decb + (long)n * 512 + m0 + tx * 4 + j,
          __float_as_uint(acc[i][j] + biasl[tx * 4 + j]));
  }
}

// ---------------- LSTM recurrence: 24 blocks (8 L0 + 16 L1) -----------------
// L0 blk 0..7  : 64 units each (256 gate rows). L1 blk 8..23: 32 units each
// (128 wih1 + 128 whh1 rows). Per thread: 16 rows — 10 in VGPR (wr[10][16]),
// 6 in LDS (stride-260 words, 2-way conflicts = free). fp16 weights + fp16
// packed h exchange; pure NaN dataflow (write-once slots, per-word retry).
__device__ void rec_path(
    char* smem,
    const float* __restrict__ ixp0,
    const float* __restrict__ wih1, const float* __restrict__ whh0,
    const float* __restrict__ whh1,
    const float* __restrict__ bih1, const float* __restrict__ bhh1,
    unsigned* __restrict__ h0s16, unsigned* __restrict__ h1s16,
    float* __restrict__ h1s32,
    float* __restrict__ hO, float* __restrict__ cO, int* __restrict__ flags)
{
  unsigned* wlu = (unsigned*)smem;                  // 96 rows * 260 words
  unsigned* hl  = (unsigned*)(smem + HL_OFF);       // [src 2][b 4][word 256]
  float*    redf = (float*)(smem + RED_OFF);        // [w4][rg16][r16][b4]
  const int tid = threadIdx.x;
  const int blk = blockIdx.x;
  const bool isL1 = blk >= 8;
  const int jb = blk - 8;
  const int rg = tid & 15, ks = tid >> 4;
  const int lane = tid & 63, wv = tid >> 6;
  int* f1 = flags + 512;

  // weight preload: rows lr = rg*16 + r; r<10 -> VGPR, r>=10 -> LDS
  h2v wr[10][16];
  unsigned* wlp = wlu + (rg * 6) * WL_WORDS_STRIDE + ks * 16;
#pragma unroll
  for (int r = 0; r < 16; ++r) {
    int lr = rg * 16 + r;
    const float* wsrc; int grow;
    if (!isL1) { int q = lr >> 6, uu = lr & 63; grow = q * 512 + blk * 64 + uu; wsrc = whh0; }
    else {
      int half = lr >> 7, rem = lr & 127;
      int q = rem >> 5, uu = rem & 31;
      grow = q * 512 + jb * 32 + uu; wsrc = half ? whh1 : wih1;
    }
    const float* wp = wsrc + (long)grow * 512 + ks * 32;
#pragma unroll
    for (int jj = 0; jj < 16; ++jj) {
      h2v t; t[0] = (_Float16)wp[2 * jj]; t[1] = (_Float16)wp[2 * jj + 1];
      if (r < 10) wr[r][jj] = t;
      else        wlp[(r - 10) * WL_WORDS_STRIDE + jj] = __builtin_bit_cast(unsigned, t);
    }
  }

  const int npair = isL1 ? 16 : 32;
  const bool eact = tid < npair * 4;
  const int ep = tid >> 2, eb = tid & 3;
  float creg[2] = {0.f, 0.f};
  float bgate[2][4];
  if (isL1 && eact) {
#pragma unroll
    for (int o = 0; o < 2; ++o)
#pragma unroll
      for (int q = 0; q < 4; ++q) {
        int grow = q * 512 + jb * 32 + 2 * ep + o;
        bgate[o][q] = bih1[grow] + bhh1[grow];
      }
  }

  const unsigned* ixu = (const unsigned*)ixp0;
  const int hsrc = (isL1 && rg >= 8) ? 1 : 0;

  for (int s = 0; s < Uc; ++s) {
    // ---- gather packed h (write-once NaN slots, per-word retry) ----
    unsigned ha[4] = {0u, 0u, 0u, 0u}, hb[4] = {0u, 0u, 0u, 0u};
    const unsigned* pa = nullptr; const unsigned* pb = nullptr;
    if (!isL1) { if (s > 0) pa = h0s16 + (long)(s - 1) * 1024 + tid * 4; }
    else {
      pa = h0s16 + (long)s * 1024 + tid * 4;
      if (s > 0) pb = h1s16 + (long)(s - 1) * 1024 + tid * 4;
    }
    if (pa) {
#pragma unroll
      for (int c = 0; c < 4; ++c) ha[c] = ldA(pa + c);
    }
    if (pb) {
#pragma unroll
      for (int c = 0; c < 4; ++c) hb[c] = ldA(pb + c);
    }

    // ---- ixp gather for L0 epilogue threads (overlaps h retries) ----
    float ixv[2][4] = {};
    if (!isL1 && eact) {
      const unsigned* ib = ixu + ((long)(eb * Uc + s) * G4 + blk * 64 + 2 * ep);
#pragma unroll
      for (int o = 0; o < 2; ++o)
#pragma unroll
        for (int q = 0; q < 4; ++q) {
          unsigned g = ldA(ib + o + q * 512);
          while (g == 0xFFFFFFFFu) { __builtin_amdgcn_s_sleep(1); g = ldA(ib + o + q * 512); }
          ixv[o][q] = __uint_as_float(g);
        }
    }

    // ---- per-word NaN backstop ----
    if (pa) {
#pragma unroll
      for (int c = 0; c < 4; ++c)
        while (ha[c] == 0xFFFFFFFFu) { __builtin_amdgcn_s_sleep(1); ha[c] = ldA(pa + c); }
    }
    if (pb) {
#pragma unroll
      for (int c = 0; c < 4; ++c)
        while (hb[c] == 0xFFFFFFFFu) { __builtin_amdgcn_s_sleep(1); hb[c] = ldA(pb + c); }
    }

    // ---- stage to LDS ----
    *(uint4*)&hl[tid * 4] = make_uint4(ha[0], ha[1], ha[2], ha[3]);
    if (isL1)
      *(uint4*)&hl[1024 + tid * 4] = make_uint4(hb[0], hb[1], hb[2], hb[3]);
    __syncthreads();

    // ---- dot via v_dot2_f32_f16, two batch passes (caps registers) ----
    const unsigned* hbase = &hl[hsrc * 1024 + ks * 16];
#pragma unroll
    for (int p = 0; p < 2; ++p) {
      float acc[16][2] = {};
#pragma unroll
      for (int jw = 0; jw < 4; ++jw) {
        uint4 t0 = *(const uint4*)&hbase[(2 * p) * 256 + jw * 4];
        uint4 t1 = *(const uint4*)&hbase[(2 * p + 1) * 256 + jw * 4];
        unsigned qb0[4] = {t0.x, t0.y, t0.z, t0.w};
        unsigned qb1[4] = {t1.x, t1.y, t1.z, t1.w};
#pragma unroll
        for (int r = 0; r < 16; ++r) {
          h2v wv2[4];
          if (r < 10) {
#pragma unroll
            for (int w = 0; w < 4; ++w) wv2[w] = wr[r][jw * 4 + w];
          } else {
            uint4 wt = *(const uint4*)&wlp[(r - 10) * WL_WORDS_STRIDE + jw * 4];
            wv2[0] = __builtin_bit_cast(h2v, wt.x);
            wv2[1] = __builtin_bit_cast(h2v, wt.y);
            wv2[2] = __builtin_bit_cast(h2v, wt.z);
            wv2[3] = __builtin_bit_cast(h2v, wt.w);
          }
#pragma unroll
          for (int w = 0; w < 4; ++w) {
            acc[r][0] = __builtin_amdgcn_fdot2(
                wv2[w], __builtin_bit_cast(h2v, qb0[w]), acc[r][0], false);
            acc[r][1] = __builtin_amdgcn_fdot2(
                wv2[w], __builtin_bit_cast(h2v, qb1[w]), acc[r][1], false);
          }
        }
      }
#pragma unroll
      for (int r = 0; r < 16; ++r)
#pragma unroll
        for (int b2 = 0; b2 < 2; ++b2) {
          float v = acc[r][b2];
          v += __shfl_xor(v, 16);
          v += __shfl_xor(v, 32);
          if (lane < 16)
            redf[((wv * 16 + lane) * 16 + r) * 4 + 2 * p + b2] = v;
        }
    }
    __syncthreads();

    // ---- epilogue: 2 units per thread, pack fp16 pair, write-once store ----
    if (eact) {
      float hn2[2], cn2[2];
#pragma unroll
      for (int o = 0; o < 2; ++o) {
        int uu = 2 * ep + o;
        float gv[4];
#pragma unroll
        for (int q = 0; q < 4; ++q) {
          float sv = 0.f;
          if (!isL1) {
            int lr = q * 64 + uu;
#pragma unroll
            for (int w = 0; w < 4; ++w)
              sv += redf[((w * 16 + (lr >> 4)) * 16 + (lr & 15)) * 4 + eb];
            sv += ixv[o][q];
          } else {
            int lrA = q * 32 + uu;          // wih1 half
            int lrB = 128 + q * 32 + uu;    // whh1 half
#pragma unroll
            for (int w = 0; w < 4; ++w) {
              sv += redf[((w * 16 + (lrA >> 4)) * 16 + (lrA & 15)) * 4 + eb];
              sv += redf[((w * 16 + (lrB >> 4)) * 16 + (lrB & 15)) * 4 + eb];
            }
            sv += bgate[o][q];
          }
          gv[q] = sv;
        }
        float cn = fsig(gv[1]) * creg[o] + fsig(gv[0]) * ftanh(gv[2]);
        float hn = fsig(gv[3]) * ftanh(cn);
        creg[o] = cn;
        hn2[o] = hn; cn2[o] = cn;
      }
      int gu = (isL1 ? jb * 32 : blk * 64) + 2 * ep;
      h2v hp; hp[0] = (_Float16)hn2[0]; hp[1] = (_Float16)hn2[1];
      unsigned pw = __builtin_bit_cast(unsigned, hp);
      stA((isL1 ? h1s16 : h0s16) + (long)s * 1024 + eb * 256 + (gu >> 1), pw);
      if (isL1) {
        unsigned* d32 = (unsigned*)h1s32 + (long)s * G4 + eb * 512 + gu;
        stA(d32, __float_as_uint(hn2[0]));
        stA(d32 + 1, __float_as_uint(hn2[1]));
      }
      if (s == Uc - 1) {
#pragma unroll
        for (int o = 0; o < 2; ++o) {
          hO[(isL1 ? G4 : 0) + eb * 512 + gu + o] = hn2[o];
          cO[(isL1 ? G4 : 0) + eb * 512 + gu + o] = cn2[o];
        }
      }
      if (isL1 && tid == 0) stA((unsigned*)(f1 + jb * 16), (unsigned)(s + 1));
    }
    __syncthreads();   // protect hl/red reuse for next step
  }
}

// ---------------- fused launch: 624 blocks x 256 threads ----------------
// 0..23 rec | 24..247 ixp | 248..311 wdc | 312..567 enc | 568..623 dec
__global__ __launch_bounds__(256, 1) void k_fused(
    const int* __restrict__ ids, const float* __restrict__ emb,
    const float* __restrict__ memory,
    const float* __restrict__ w_ih, const float* __restrict__ b_ih,
    const float* __restrict__ b_hh,
    const float* __restrict__ wih1, const float* __restrict__ whh0,
    const float* __restrict__ whh1,
    const float* __restrict__ bih1, const float* __restrict__ bhh1,
    const float* __restrict__ jw1, const float* __restrict__ jb1,
    const float* __restrict__ fc_w, const float* __restrict__ fc_b,
    float* __restrict__ ixp0, unsigned* __restrict__ h0s16,
    unsigned* __restrict__ h1s16, float* __restrict__ h1s32,
    float* __restrict__ wdc, float* __restrict__ decb, float* __restrict__ encb,
    float* __restrict__ hO, float* __restrict__ cO, int* __restrict__ flags)
{
  __shared__ __attribute__((aligned(16))) char smem[SMEM_BYTES];
  const int blk = blockIdx.x;
  if (blk < 24) {
    rec_path(smem, ixp0, wih1, whh0, whh1, bih1, bhh1, h0s16, h1s16, h1s32,
             hO, cO, flags);
  } else if (blk < 248) {
    static const int nt_ord[7] = {0, 1, 3, 4, 2, 5, 6};
    int g = blk - 24;
    gemm_tile<1>(smem, nullptr, 0, w_ih, 512, b_ih, b_hh,
                 ixp0, G4, Bc * Uc, (g % 32) * 64, nt_ord[g / 32] * 64, ids, emb);
  } else if (blk < 312) {
    int g = blk - 248;
    wdc_tile(smem, jw1, fc_w, wdc, (g & 7) * 64, (g >> 3) * 64);
  } else if (blk < 568) {
    int g = blk - 312;
    gemm_tile<0>(smem, memory, 512, jw1, 1024, nullptr, nullptr,
                 encb, 512, Bc * Tc, (g & 7) * 64, (g >> 3) * 64, nullptr, nullptr);
  } else {
    int g = blk - 568;
    dec_tile(smem, h1s32, wdc, jw1, fc_b, jb1, decb, flags + 512,
             (g & 7) * 64, (g >> 3) * 64);
  }
}

// ---------------- joint via bf16 MFMA (unchanged) ----------------
__global__ __launch_bounds__(256) void k_jmfma(
    const float* __restrict__ enc, const float* __restrict__ dec,
    const float* __restrict__ jw2, const float* __restrict__ jb2,
    float* __restrict__ out)
{
  __shared__ float el[512];
  __shared__ short th[112][136];
  const int tid = threadIdx.x;
  const int lane = tid & 63, wv = tid >> 6;
  const int bt = blockIdx.x;
  const int b = bt / Tc;
  const int v0 = wv * 16;
  const int vl = lane & 15, kg = lane >> 4;

  short8v breg[16];
#pragma unroll
  for (int ksx = 0; ksx < 16; ++ksx) {
    const float* wp = jw2 + (long)(v0 + vl) * 512 + ksx * 32 + kg * 8;
    float4 x0 = *(const float4*)wp;
    float4 x1 = *(const float4*)(wp + 4);
    short8v t;
    t[0] = f2bf(x0.x); t[1] = f2bf(x0.y); t[2] = f2bf(x0.z); t[3] = f2bf(x0.w);
    t[4] = f2bf(x1.x); t[5] = f2bf(x1.y); t[6] = f2bf(x1.z); t[7] = f2bf(x1.w);
    breg[ksx] = t;
  }
  const float jbv = jb2[v0 + vl];
  for (int i = tid; i < 512; i += 256) el[i] = enc[(long)bt * 512 + i];

  f32x4 acc[7];
#pragma unroll
  for (int ut = 0; ut < 7; ++ut) acc[ut] = (f32x4){0.f, 0.f, 0.f, 0.f};
  __syncthreads();

  const float* dec0 = dec + (long)b * Uc * 512;
  for (int kc = 0; kc < 4; ++kc) {
#pragma unroll 5
    for (int it = 0; it < 50; ++it) {
      int flat = it * 256 + tid;
      int u = flat >> 7, kk = flat & 127;
      float dv = dec0[(long)u * 512 + kc * 128 + kk];
      th[u][kk] = f2bf(ftanh(el[kc * 128 + kk] + dv));
    }
    __syncthreads();
#pragma unroll
    for (int ks4 = 0; ks4 < 4; ++ks4) {
      int ko = ks4 * 32 + kg * 8;
#pragma unroll
      for (int ut = 0; ut < 7; ++ut) {
        short8v a = *(const short8v*)&th[ut * 16 + vl][ko];
        acc[ut] = __builtin_amdgcn_mfma_f32_16x16x32_bf16(a, breg[kc * 4 + ks4],
                                                          acc[ut], 0, 0, 0);
      }
    }
    __syncthreads();
  }
#pragma unroll
  for (int ut = 0; ut < 7; ++ut) {
#pragma unroll
    for (int i = 0; i < 4; ++i) {
      int u = ut * 16 + kg * 4 + i;
      if (u < Uc)
        out[((long)bt * Uc + u) * 64 + v0 + vl] = acc[ut][i] + jbv;
    }
  }
}

extern "C" void kernel_launch(void* const* d_in, const int* in_sizes, int n_in,
                              void* d_out, int out_size, void* d_ws, size_t ws_size,
                              hipStream_t stream)
{
  const int*   ids    = (const int*)d_in[0];
  const float* memory = (const float*)d_in[1];
  const float* emb    = (const float*)d_in[2];
  const float* w_ih   = (const float*)d_in[3];
  const float* w_hh   = (const float*)d_in[4];
  const float* b_ih   = (const float*)d_in[5];
  const float* b_hh   = (const float*)d_in[6];
  const float* fc_w   = (const float*)d_in[7];
  const float* fc_b   = (const float*)d_in[8];
  const float* jw1    = (const float*)d_in[9];
  const float* jb1    = (const float*)d_in[10];
  const float* jw2    = (const float*)d_in[11];
  const float* jb2    = (const float*)d_in[12];
  float* out = (float*)d_out;

  float* wsf = (float*)d_ws;
  int*      flags = (int*)d_ws;                      // 4096 ints (f1 at +512)
  float*    ixp0  = wsf + 4096;                      // 819200
  unsigned* h0s16 = (unsigned*)(wsf + 823296);       // 102400 words
  unsigned* h1s16 = (unsigned*)(wsf + 925696);       // 102400 words
  float*    h1s32 = wsf + 1028096;                   // 204800
  float*    wdc   = wsf + 1232896;                   // 262144
  float*    decb  = wsf + 1495040;                   // 204800
  float*    encb  = wsf + 1699840;                   // 1024000

  float* hO = out + (long)Bc * Tc * Uc * Vc;
  float* cO = hO + 2 * Bc * 512;

  // flags = 0; NaN-init dataflow regions (ixp0,h0s16,h1s16,h1s32,wdc,decb)
  hipMemsetAsync(flags, 0, 4096 * 4, stream);
  hipMemsetAsync(ixp0, 0xFF, (size_t)(1699840 - 4096) * 4, stream);

  k_fused<<<624, 256, 0, stream>>>(ids, emb, memory,
                                   w_ih, b_ih, b_hh,
                                   w_ih + (long)G4 * 512,  // wih1
                                   w_hh,                   // whh0
                                   w_hh + (long)G4 * 512,  // whh1
                                   b_ih + G4, b_hh + G4,
                                   jw1, jb1, fc_w, fc_b,
                                   ixp0, h0s16, h1s16, h1s32, wdc, decb, encb,
                                   hO, cO, flags);

  k_jmfma<<<2000, 256, 0, stream>>>(encb, decb, jw2, jb2, out);
}

// Round 12
// 832.797 us; speedup vs baseline: 1.8192x; 1.8192x over previous
//
#include <hip/hip_runtime.h>

#define Bc 4
#define Tc 500
#define Uc 100
#define Vc 64
#define G4 2048

typedef __attribute__((ext_vector_type(8))) short short8v;
typedef __attribute__((ext_vector_type(4))) float f32x4;
typedef _Float16 h2v __attribute__((ext_vector_type(2)));

__device__ __forceinline__ float fsig(float x) {
  return __builtin_amdgcn_rcpf(1.f + __expf(-x));
}
__device__ __forceinline__ float ftanh(float x) {
  float e = __expf(2.f * x);
  return 1.f - 2.f * __builtin_amdgcn_rcpf(e + 1.f);
}
__device__ __forceinline__ short f2bf(float f) {
  unsigned u = __float_as_uint(f);
  unsigned r = (u + 0x7FFFu + ((u >> 16) & 1u)) >> 16;
  return (short)r;
}

__device__ __forceinline__ unsigned ldA(const unsigned* p) {
  return __hip_atomic_load(p, __ATOMIC_RELAXED, __HIP_MEMORY_SCOPE_AGENT);
}
__device__ __forceinline__ void stA(unsigned* p, unsigned v) {
  __hip_atomic_store(p, v, __ATOMIC_RELAXED, __HIP_MEMORY_SCOPE_AGENT);
}
// XCD-local (same-XCD L2) exchange ops: L1-bypass load (sc0), plain store
// (L1 is write-through so the store lands in the XCD's L2).
__device__ __forceinline__ unsigned ldL2(const unsigned* p) {
  unsigned v;
  asm volatile("global_load_dword %0, %1, off sc0\n\ts_waitcnt vmcnt(0)"
               : "=v"(v) : "v"(p) : "memory");
  return v;
}
__device__ __forceinline__ uint4 ldL2x4(const unsigned* p) {
  uint4 v;
  asm volatile("global_load_dwordx4 %0, %1, off sc0\n\ts_waitcnt vmcnt(0)"
               : "=v"(v) : "v"(p) : "memory");
  return v;
}
__device__ __forceinline__ void stL2(unsigned* p, unsigned v) {
  *(volatile unsigned*)p = v;
}

// ---------------- generic GEMM tile (r10-identical) ----------------
template <int ATOMICST>
__device__ __forceinline__ void gemm_tile(
    const float* __restrict__ A, int lda,
    const float* __restrict__ Bw, int ldb,
    const float* __restrict__ bias, const float* __restrict__ bias2,
    float* __restrict__ C, int ldc, int N, int m0, int n0,
    const int* __restrict__ ids, const float* __restrict__ emb)
{
  __shared__ float As[16][65];
  __shared__ float Bs[16][65];
  const int tid = threadIdx.x;
  const int tx = tid & 15, ty = tid >> 4;
  float acc[4][4] = {};
  for (int k0 = 0; k0 < 512; k0 += 16) {
#pragma unroll
    for (int i = 0; i < 4; ++i) {
      int n = n0 + ty + 16 * i;
      float av = 0.f;
      if (n < N) {
        const float* ar = ids ? (emb + (long)ids[n] * 512) : (A + (long)n * lda);
        av = ar[k0 + tx];
      }
      As[tx][ty + 16 * i] = av;
      Bs[tx][ty + 16 * i] = Bw[(long)(m0 + ty + 16 * i) * ldb + k0 + tx];
    }
    __syncthreads();
#pragma unroll
    for (int kl = 0; kl < 16; ++kl) {
      float a[4], b[4];
#pragma unroll
      for (int i = 0; i < 4; ++i) a[i] = As[kl][ty * 4 + i];
#pragma unroll
      for (int j = 0; j < 4; ++j) b[j] = Bs[kl][tx * 4 + j];
#pragma unroll
      for (int i = 0; i < 4; ++i)
#pragma unroll
        for (int j = 0; j < 4; ++j) acc[i][j] += a[i] * b[j];
    }
    __syncthreads();
  }
#pragma unroll
  for (int i = 0; i < 4; ++i) {
    int n = n0 + ty * 4 + i;
    if (n >= N) continue;
#pragma unroll
    for (int j = 0; j < 4; ++j) {
      int m = m0 + tx * 4 + j;
      float v = acc[i][j];
      if (bias)  v += bias[m];
      if (bias2) v += bias2[m];
      if (ATOMICST)
        stA((unsigned*)C + (long)n * ldc + m, __float_as_uint(v));
      else
        C[(long)n * ldc + m] = v;
    }
  }
}

// ---------------- wdc tile (r10-identical) ----------------
__device__ void wdc_tile(const float* __restrict__ jw1,
                         const float* __restrict__ fc_w,
                         float* __restrict__ wdc, int n0, int m0)
{
  __shared__ float As[16][65];
  __shared__ float Bs[16][65];
  const int tid = threadIdx.x;
  const int tx = tid & 15, ty = tid >> 4;
  float acc[4][4] = {};
  for (int k0 = 0; k0 < 512; k0 += 16) {
#pragma unroll
    for (int i = 0; i < 4; ++i) {
      As[tx][ty + 16 * i] = jw1[(long)(n0 + ty + 16 * i) * 1024 + 512 + k0 + tx];
      Bs[ty][tx + 16 * i] = fc_w[(long)(k0 + ty) * 512 + m0 + tx + 16 * i];
    }
    __syncthreads();
#pragma unroll
    for (int kl = 0; kl < 16; ++kl) {
      float a[4], b[4];
#pragma unroll
      for (int i = 0; i < 4; ++i) a[i] = As[kl][ty * 4 + i];
#pragma unroll
      for (int j = 0; j < 4; ++j) b[j] = Bs[kl][tx * 4 + j];
#pragma unroll
      for (int i = 0; i < 4; ++i)
#pragma unroll
        for (int j = 0; j < 4; ++j) acc[i][j] += a[i] * b[j];
    }
    __syncthreads();
  }
#pragma unroll
  for (int i = 0; i < 4; ++i)
#pragma unroll
    for (int j = 0; j < 4; ++j)
      stA((unsigned*)wdc + (long)(n0 + ty * 4 + i) * 512 + m0 + tx * 4 + j,
          __float_as_uint(acc[i][j]));
}

// ---------------- dec tile (r10-identical) ----------------
__device__ void dec_tile(const float* __restrict__ h1s, const float* __restrict__ wdc,
                         const float* __restrict__ jw1, const float* __restrict__ fc_b,
                         const float* __restrict__ jb1, float* __restrict__ decb,
                         const int* __restrict__ f1, int m0, int n0)
{
  __shared__ float As[16][65];
  __shared__ float Bs[16][65];
  __shared__ float biasl[64];
  const int tid = threadIdx.x;
  const int tx = tid & 15, ty = tid >> 4;
  int u_hi = 0;
  for (int rr = 0; rr < 64; ++rr) {
    int r = n0 + rr;
    if (r < 400) { int u = r % Uc; u_hi = max(u_hi, u + 1); }
  }
  if (tid < 32)
    while ((int)ldA((const unsigned*)(f1 + tid * 16)) < u_hi)
      __builtin_amdgcn_s_sleep(8);
  if (tid < 64) {
    int m = m0 + tid;
    const float4* wp = (const float4*)(jw1 + (long)m * 1024 + 512);
    const float4* fb = (const float4*)fc_b;
    float bb = jb1[m];
#pragma unroll 8
    for (int d4 = 0; d4 < 128; ++d4) {
      float4 w = wp[d4], f = fb[d4];
      bb += w.x * f.x + w.y * f.y + w.z * f.z + w.w * f.w;
    }
    biasl[tid] = bb;
  }
  __syncthreads();
  const unsigned* h1u = (const unsigned*)h1s;
  const unsigned* wdu = (const unsigned*)wdc;
  float acc[4][4] = {};
  for (int k0 = 0; k0 < 512; k0 += 16) {
    unsigned uA[4], uB[4];
#pragma unroll
    for (int i = 0; i < 4; ++i) {
      int n = n0 + ty + 16 * i;
      uA[i] = (n < 400) ? ldA(h1u + (long)(n % Uc) * G4 + (n / Uc) * 512 + k0 + tx) : 0u;
      uB[i] = ldA(wdu + (long)(m0 + ty + 16 * i) * 512 + k0 + tx);
    }
#pragma unroll
    for (int i = 0; i < 4; ++i) {
      int n = n0 + ty + 16 * i;
      while (uA[i] == 0xFFFFFFFFu)
        uA[i] = ldA(h1u + (long)(n % Uc) * G4 + (n / Uc) * 512 + k0 + tx);
      while (uB[i] == 0xFFFFFFFFu)
        uB[i] = ldA(wdu + (long)(m0 + ty + 16 * i) * 512 + k0 + tx);
      As[tx][ty + 16 * i] = __uint_as_float(uA[i]);
      Bs[tx][ty + 16 * i] = __uint_as_float(uB[i]);
    }
    __syncthreads();
#pragma unroll
    for (int kl = 0; kl < 16; ++kl) {
      float a[4], b[4];
#pragma unroll
      for (int i = 0; i < 4; ++i) a[i] = As[kl][ty * 4 + i];
#pragma unroll
      for (int j = 0; j < 4; ++j) b[j] = Bs[kl][tx * 4 + j];
#pragma unroll
      for (int i = 0; i < 4; ++i)
#pragma unroll
        for (int j = 0; j < 4; ++j) acc[i][j] += a[i] * b[j];
    }
    __syncthreads();
  }
#pragma unroll
  for (int i = 0; i < 4; ++i) {
    int n = n0 + ty * 4 + i;
    if (n >= 400) continue;
#pragma unroll
    for (int j = 0; j < 4; ++j)
      stA((unsigned*)decb + (long)n * 512 + m0 + tx * 4 + j,
          __float_as_uint(acc[i][j] + biasl[tx * 4 + j]));
  }
}

// ---------------- LSTM recurrence (r10 structure; role-indexed; dual-mode) --
// role 0..15 : layer 0, 32 units each. role 16..47: layer 1, 16 units each.
// fp16 weights in VGPRs (v_dot2_f32_f16); fp16-packed write-once NaN h slots.
// Mode vote: if all 48 roles share one XCD -> exchange via XCD-local L2
// (plain store + sc0 load); else agent-scope fallback (r10-identical).
__device__ void rec_path(
    int role,
    const float* __restrict__ ixp0,
    const float* __restrict__ wih1, const float* __restrict__ whh0,
    const float* __restrict__ whh1,
    const float* __restrict__ bih1, const float* __restrict__ bhh1,
    unsigned* __restrict__ h0s16, unsigned* __restrict__ h1s16,
    float* __restrict__ h1s32,
    float* __restrict__ hO, float* __restrict__ cO,
    int* __restrict__ flags, int* __restrict__ xtab)
{
  __shared__ unsigned hl[2048];
  __shared__ float4 red4[512];
  __shared__ int mode_s;
  const int tid = threadIdx.x;
  const bool isL1 = role >= 16;
  const int jb = role - 16;
  const int rg = tid & 15, ks = tid >> 4;
  const int lane = tid & 63, wv = tid >> 6;
  int* f1 = flags + 512;

  // ---- mode vote: all 48 roles on one XCD? ----
  if (tid < 64) {
    int idx = (tid < 48) ? tid : 47;
    unsigned v = ldA((const unsigned*)(xtab + idx * 16));
    while (v == 0u) { __builtin_amdgcn_s_sleep(4); v = ldA((const unsigned*)(xtab + idx * 16)); }
    unsigned v0 = __shfl(v, 0);
    unsigned long long ball = __ballot(v == v0);
    if (tid == 0) mode_s = (ball == ~0ull) ? 1 : 0;
  }
  __syncthreads();
  const bool fastm = (mode_s != 0);

  // fp16 weight preload: 8 rows x 32 k -> 128 VGPRs
  h2v wr[8][16];
#pragma unroll
  for (int r = 0; r < 8; ++r) {
    int lr = rg * 8 + r;
    const float* wsrc; int grow;
    if (!isL1) { int q = lr >> 5, uu = lr & 31; grow = q * 512 + role * 32 + uu; wsrc = whh0; }
    else {
      if (lr < 64) { int q = lr >> 4, uu = lr & 15; grow = q * 512 + jb * 16 + uu; wsrc = wih1; }
      else { int l2 = lr - 64; int q = l2 >> 4, uu = l2 & 15; grow = q * 512 + jb * 16 + uu; wsrc = whh1; }
    }
    const float* wp = wsrc + (long)grow * 512 + ks * 32;
#pragma unroll
    for (int jj = 0; jj < 16; ++jj) {
      h2v t; t[0] = (_Float16)wp[2 * jj]; t[1] = (_Float16)wp[2 * jj + 1];
      wr[r][jj] = t;
    }
  }

  const int npair = isL1 ? 8 : 16;
  const bool eact = tid < npair * 4;
  const int ep = tid >> 2, eb = tid & 3;
  float creg[2] = {0.f, 0.f};
  float bgate[2][4];
  if (isL1 && eact) {
#pragma unroll
    for (int o = 0; o < 2; ++o)
#pragma unroll
      for (int q = 0; q < 4; ++q) {
        int grow = q * 512 + jb * 16 + 2 * ep + o;
        bgate[o][q] = bih1[grow] + bhh1[grow];
      }
  }

  const unsigned* ixu = (const unsigned*)ixp0;
  const int hsrc = (isL1 && rg >= 8) ? 1 : 0;
  const float* redf = (const float*)red4;

  // ---- ixp prefetch (L0 feed is dependency-free: fetch 1 step ahead) ----
  unsigned ixn[8];
  const unsigned* ib0 = (!isL1 && eact)
      ? ixu + ((long)(eb * Uc) * G4 + role * 32 + 2 * ep) : nullptr;
  if (ib0) {
#pragma unroll
    for (int o = 0; o < 2; ++o)
#pragma unroll
      for (int q = 0; q < 4; ++q) ixn[o * 4 + q] = ldA(ib0 + o + q * 512);
  }

  for (int s = 0; s < Uc; ++s) {
    // ---- gather packed h (write-once NaN slots) ----
    unsigned ha[4] = {0u, 0u, 0u, 0u}, hb[4] = {0u, 0u, 0u, 0u};
    const unsigned* pa = nullptr; const unsigned* pb = nullptr;
    if (!isL1) { if (s > 0) pa = h0s16 + (long)(s - 1) * 1024 + tid * 4; }
    else {
      pa = h0s16 + (long)s * 1024 + tid * 4;
      if (s > 0) pb = h1s16 + (long)(s - 1) * 1024 + tid * 4;
    }
    if (fastm) {
      if (pa) { uint4 t = ldL2x4(pa); ha[0] = t.x; ha[1] = t.y; ha[2] = t.z; ha[3] = t.w; }
      if (pb) { uint4 t = ldL2x4(pb); hb[0] = t.x; hb[1] = t.y; hb[2] = t.z; hb[3] = t.w; }
    } else {
      if (pa) {
#pragma unroll
        for (int c = 0; c < 4; ++c) ha[c] = ldA(pa + c);
      }
      if (pb) {
#pragma unroll
        for (int c = 0; c < 4; ++c) hb[c] = ldA(pb + c);
      }
    }

    // ---- consume prefetched ixp (retry rare stragglers) ----
    float ixv[2][4] = {};
    if (ib0) {
      const unsigned* ib = ib0 + (long)s * G4;
#pragma unroll
      for (int o = 0; o < 2; ++o)
#pragma unroll
        for (int q = 0; q < 4; ++q) {
          unsigned g = ixn[o * 4 + q];
          while (g == 0xFFFFFFFFu) { __builtin_amdgcn_s_sleep(1); g = ldA(ib + o + q * 512); }
          ixv[o][q] = __uint_as_float(g);
        }
    }

    // ---- per-word NaN backstop on h ----
    if (pa) {
#pragma unroll
      for (int c = 0; c < 4; ++c)
        while (ha[c] == 0xFFFFFFFFu) {
          __builtin_amdgcn_s_sleep(1);
          ha[c] = fastm ? ldL2(pa + c) : ldA(pa + c);
        }
    }
    if (pb) {
#pragma unroll
      for (int c = 0; c < 4; ++c)
        while (hb[c] == 0xFFFFFFFFu) {
          __builtin_amdgcn_s_sleep(1);
          hb[c] = fastm ? ldL2(pb + c) : ldA(pb + c);
        }
    }

    // ---- prefetch ixp for s+1 (stays in flight through the dot) ----
    if (ib0 && s + 1 < Uc) {
      const unsigned* ibn = ib0 + (long)(s + 1) * G4;
#pragma unroll
      for (int o = 0; o < 2; ++o)
#pragma unroll
        for (int q = 0; q < 4; ++q) ixn[o * 4 + q] = ldA(ibn + o + q * 512);
    }

    // ---- stage to LDS ----
    *(uint4*)&hl[tid * 4] = make_uint4(ha[0], ha[1], ha[2], ha[3]);
    if (isL1)
      *(uint4*)&hl[1024 + tid * 4] = make_uint4(hb[0], hb[1], hb[2], hb[3]);
    __syncthreads();

    // ---- dot via v_dot2_f32_f16 ----
    float acc[8][4] = {};
    const unsigned* hbase = &hl[hsrc * 1024 + ks * 16];
#pragma unroll
    for (int jw = 0; jw < 4; ++jw) {
      unsigned q[4][4];
#pragma unroll
      for (int b = 0; b < 4; ++b) {
        uint4 t = *(const uint4*)&hbase[b * 256 + jw * 4];
        q[b][0] = t.x; q[b][1] = t.y; q[b][2] = t.z; q[b][3] = t.w;
      }
#pragma unroll
      for (int r = 0; r < 8; ++r)
#pragma unroll
        for (int w = 0; w < 4; ++w) {
          h2v wv2 = wr[r][jw * 4 + w];
#pragma unroll
          for (int b = 0; b < 4; ++b)
            acc[r][b] = __builtin_amdgcn_fdot2(
                wv2, __builtin_bit_cast(h2v, q[b][w]), acc[r][b], false);
        }
    }
#pragma unroll
    for (int r = 0; r < 8; ++r)
#pragma unroll
      for (int b = 0; b < 4; ++b) {
        float v = acc[r][b];
        v += __shfl_xor(v, 16);
        v += __shfl_xor(v, 32);
        acc[r][b] = v;
      }
    if (lane < 16) {
#pragma unroll
      for (int r = 0; r < 8; ++r)
        red4[wv * 128 + lane * 8 + r] =
            make_float4(acc[r][0], acc[r][1], acc[r][2], acc[r][3]);
    }
    __syncthreads();

    // ---- epilogue: 2 units per thread, pack fp16 pair, write-once store ----
    if (eact) {
      float hn2[2], cn2[2];
#pragma unroll
      for (int o = 0; o < 2; ++o) {
        int uu = 2 * ep + o;
        float gv[4];
#pragma unroll
        for (int q = 0; q < 4; ++q) {
          int lrA = isL1 ? (q * 16 + uu) : (q * 32 + uu);
          float sv = 0.f;
#pragma unroll
          for (int w = 0; w < 4; ++w)
            sv += redf[(w * 128 + (lrA >> 3) * 8 + (lrA & 7)) * 4 + eb];
          if (isL1) {
            int lrB = 64 + q * 16 + uu;
#pragma unroll
            for (int w = 0; w < 4; ++w)
              sv += redf[(w * 128 + (lrB >> 3) * 8 + (lrB & 7)) * 4 + eb];
            sv += bgate[o][q];
          } else {
            sv += ixv[o][q];
          }
          gv[q] = sv;
        }
        float cn = fsig(gv[1]) * creg[o] + fsig(gv[0]) * ftanh(gv[2]);
        float hn = fsig(gv[3]) * ftanh(cn);
        creg[o] = cn;
        hn2[o] = hn; cn2[o] = cn;
      }
      int gu = (isL1 ? jb * 16 : role * 32) + 2 * ep;
      h2v hp; hp[0] = (_Float16)hn2[0]; hp[1] = (_Float16)hn2[1];
      unsigned pw = __builtin_bit_cast(unsigned, hp);
      unsigned* d16 = (isL1 ? h1s16 : h0s16) + (long)s * 1024 + eb * 256 + (gu >> 1);
      if (fastm) stL2(d16, pw); else stA(d16, pw);
      if (isL1) {
        unsigned* d32 = (unsigned*)h1s32 + (long)s * G4 + eb * 512 + gu;
        stA(d32, __float_as_uint(hn2[0]));
        stA(d32 + 1, __float_as_uint(hn2[1]));
      }
      if (s == Uc - 1) {
#pragma unroll
        for (int o = 0; o < 2; ++o) {
          hO[(isL1 ? G4 : 0) + eb * 512 + gu + o] = hn2[o];
          cO[(isL1 ? G4 : 0) + eb * 512 + gu + o] = cn2[o];
        }
      }
      if (isL1 && tid == 0) stA((unsigned*)(f1 + jb * 16), (unsigned)(s + 1));
    }
  }
}

// ---------------- fused launch: 648 blocks, role-ticketed ----------------
__global__ __launch_bounds__(256, 1) void k_fused(
    const int* __restrict__ ids, const float* __restrict__ emb,
    const float* __restrict__ memory,
    const float* __restrict__ w_ih, const float* __restrict__ b_ih,
    const float* __restrict__ b_hh,
    const float* __restrict__ wih1, const float* __restrict__ whh0,
    const float* __restrict__ whh1,
    const float* __restrict__ bih1, const float* __restrict__ bhh1,
    const float* __restrict__ jw1, const float* __restrict__ jb1,
    const float* __restrict__ fc_w, const float* __restrict__ fc_b,
    float* __restrict__ ixp0, unsigned* __restrict__ h0s16,
    unsigned* __restrict__ h1s16, float* __restrict__ h1s32,
    float* __restrict__ wdc, float* __restrict__ decb, float* __restrict__ encb,
    float* __restrict__ hO, float* __restrict__ cO, int* __restrict__ flags)
{
  __shared__ int role_s[2];
  int* rec_tk = flags + 1024;
  int* wrk_tk = flags + 1040;
  int* xtab   = flags + 1088;   // 48 entries, 16-int stride
  if (threadIdx.x == 0) {
    unsigned xcd;
    asm volatile("s_getreg_b32 %0, hwreg(HW_REG_XCC_ID)" : "=s"(xcd));
    xcd &= 7u;
    int role = -1;
    if (xcd == 0u) {
      int r = __hip_atomic_fetch_add(rec_tk, 1, __ATOMIC_RELAXED, __HIP_MEMORY_SCOPE_AGENT);
      if (r < 48) role = r;
    } else {
      for (int it = 0; it < 64; ++it) {
        if ((int)ldA((const unsigned*)rec_tk) >= 48) break;
        __builtin_amdgcn_s_sleep(8);
      }
      if ((int)ldA((const unsigned*)rec_tk) < 48) {
        int r = __hip_atomic_fetch_add(rec_tk, 1, __ATOMIC_RELAXED, __HIP_MEMORY_SCOPE_AGENT);
        if (r < 48) role = r;
      }
    }
    int wrk = -1;
    if (role < 0)
      wrk = __hip_atomic_fetch_add(wrk_tk, 1, __ATOMIC_RELAXED, __HIP_MEMORY_SCOPE_AGENT);
    else
      stA((unsigned*)(xtab + role * 16), xcd + 1u);
    role_s[0] = role; role_s[1] = wrk;
  }
  __syncthreads();
  const int role = role_s[0];
  const int w = role_s[1];

  if (role >= 0) {
    rec_path(role, ixp0, wih1, whh0, whh1, bih1, bhh1, h0s16, h1s16, h1s32,
             hO, cO, flags, xtab);
  } else if (w < 224) {
    static const int nt_ord[7] = {0, 1, 3, 4, 2, 5, 6};
    gemm_tile<1>(nullptr, 0, w_ih, 512, b_ih, b_hh,
                 ixp0, G4, Bc * Uc, (w % 32) * 64, nt_ord[w / 32] * 64, ids, emb);
  } else if (w < 288) {
    int g = w - 224;
    wdc_tile(jw1, fc_w, wdc, (g & 7) * 64, (g >> 3) * 64);
  } else if (w < 544) {
    int g = w - 288;
    gemm_tile<0>(memory, 512, jw1, 1024, nullptr, nullptr,
                 encb, 512, Bc * Tc, (g & 7) * 64, (g >> 3) * 64, nullptr, nullptr);
  } else if (w < 600) {
    int g = w - 544;
    dec_tile(h1s32, wdc, jw1, fc_b, jb1, decb, flags + 512, (g & 7) * 64, (g >> 3) * 64);
  }
}

// ---------------- joint via bf16 MFMA (unchanged) ----------------
__global__ __launch_bounds__(256) void k_jmfma(
    const float* __restrict__ enc, const float* __restrict__ dec,
    const float* __restrict__ jw2, const float* __restrict__ jb2,
    float* __restrict__ out)
{
  __shared__ float el[512];
  __shared__ short th[112][136];
  const int tid = threadIdx.x;
  const int lane = tid & 63, wv = tid >> 6;
  const int bt = blockIdx.x;
  const int b = bt / Tc;
  const int v0 = wv * 16;
  const int vl = lane & 15, kg = lane >> 4;

  short8v breg[16];
#pragma unroll
  for (int ksx = 0; ksx < 16; ++ksx) {
    const float* wp = jw2 + (long)(v0 + vl) * 512 + ksx * 32 + kg * 8;
    float4 x0 = *(const float4*)wp;
    float4 x1 = *(const float4*)(wp + 4);
    short8v t;
    t[0] = f2bf(x0.x); t[1] = f2bf(x0.y); t[2] = f2bf(x0.z); t[3] = f2bf(x0.w);
    t[4] = f2bf(x1.x); t[5] = f2bf(x1.y); t[6] = f2bf(x1.z); t[7] = f2bf(x1.w);
    breg[ksx] = t;
  }
  const float jbv = jb2[v0 + vl];
  for (int i = tid; i < 512; i += 256) el[i] = enc[(long)bt * 512 + i];

  f32x4 acc[7];
#pragma unroll
  for (int ut = 0; ut < 7; ++ut) acc[ut] = (f32x4){0.f, 0.f, 0.f, 0.f};
  __syncthreads();

  const float* dec0 = dec + (long)b * Uc * 512;
  for (int kc = 0; kc < 4; ++kc) {
#pragma unroll 5
    for (int it = 0; it < 50; ++it) {
      int flat = it * 256 + tid;
      int u = flat >> 7, kk = flat & 127;
      float dv = dec0[(long)u * 512 + kc * 128 + kk];
      th[u][kk] = f2bf(ftanh(el[kc * 128 + kk] + dv));
    }
    __syncthreads();
#pragma unroll
    for (int ks4 = 0; ks4 < 4; ++ks4) {
      int ko = ks4 * 32 + kg * 8;
#pragma unroll
      for (int ut = 0; ut < 7; ++ut) {
        short8v a = *(const short8v*)&th[ut * 16 + vl][ko];
        acc[ut] = __builtin_amdgcn_mfma_f32_16x16x32_bf16(a, breg[kc * 4 + ks4],
                                                          acc[ut], 0, 0, 0);
      }
    }
    __syncthreads();
  }
#pragma unroll
  for (int ut = 0; ut < 7; ++ut) {
#pragma unroll
    for (int i = 0; i < 4; ++i) {
      int u = ut * 16 + kg * 4 + i;
      if (u < Uc)
        out[((long)bt * Uc + u) * 64 + v0 + vl] = acc[ut][i] + jbv;
    }
  }
}

extern "C" void kernel_launch(void* const* d_in, const int* in_sizes, int n_in,
                              void* d_out, int out_size, void* d_ws, size_t ws_size,
                              hipStream_t stream)
{
  const int*   ids    = (const int*)d_in[0];
  const float* memory = (const float*)d_in[1];
  const float* emb    = (const float*)d_in[2];
  const float* w_ih   = (const float*)d_in[3];
  const float* w_hh   = (const float*)d_in[4];
  const float* b_ih   = (const float*)d_in[5];
  const float* b_hh   = (const float*)d_in[6];
  const float* fc_w   = (const float*)d_in[7];
  const float* fc_b   = (const float*)d_in[8];
  const float* jw1    = (const float*)d_in[9];
  const float* jb1    = (const float*)d_in[10];
  const float* jw2    = (const float*)d_in[11];
  const float* jb2    = (const float*)d_in[12];
  float* out = (float*)d_out;

  float* wsf = (float*)d_ws;
  int*      flags = (int*)d_ws;                      // 4096 ints: f1 | tickets | xtab
  float*    ixp0  = wsf + 4096;                      // 819200
  unsigned* h0s16 = (unsigned*)(wsf + 823296);       // 102400 words
  unsigned* h1s16 = (unsigned*)(wsf + 925696);       // 102400 words
  float*    h1s32 = wsf + 1028096;                   // 204800
  float*    wdc   = wsf + 1232896;                   // 262144
  float*    decb  = wsf + 1495040;                   // 204800
  float*    encb  = wsf + 1699840;                   // 1024000

  float* hO = out + (long)Bc * Tc * Uc * Vc;
  float* cO = hO + 2 * Bc * 512;

  // flags/tickets/xtab = 0; NaN-init dataflow regions
  hipMemsetAsync(flags, 0, 4096 * 4, stream);
  hipMemsetAsync(ixp0, 0xFF, (size_t)(1699840 - 4096) * 4, stream);

  k_fused<<<648, 256, 0, stream>>>(ids, emb, memory,
                                   w_ih, b_ih, b_hh,
                                   w_ih + (long)G4 * 512,  // wih1
                                   w_hh,                   // whh0
                                   w_hh + (long)G4 * 512,  // whh1
                                   b_ih + G4, b_hh + G4,
                                   jw1, jb1, fc_w, fc_b,
                                   ixp0, h0s16, h1s16, h1s32, wdc, decb, encb,
                                   hO, cO, flags);

  k_jmfma<<<2000, 256, 0, stream>>>(encb, decb, jw2, jb2, out);
}

// Round 13
// 706.628 us; speedup vs baseline: 2.1440x; 1.1786x over previous
//
#include <hip/hip_runtime.h>

#define Bc 4
#define Tc 500
#define Uc 100
#define Vc 64
#define G4 2048

typedef __attribute__((ext_vector_type(8))) short short8v;
typedef __attribute__((ext_vector_type(4))) float f32x4;
typedef _Float16 h2v __attribute__((ext_vector_type(2)));

#define SMEM_BYTES 86016   // >80KB -> 1 block/CU (exclusive CU per block)

__device__ __forceinline__ float fsig(float x) {
  return __builtin_amdgcn_rcpf(1.f + __expf(-x));
}
__device__ __forceinline__ float ftanh(float x) {
  float e = __expf(2.f * x);
  return 1.f - 2.f * __builtin_amdgcn_rcpf(e + 1.f);
}
__device__ __forceinline__ short f2bf(float f) {
  unsigned u = __float_as_uint(f);
  unsigned r = (u + 0x7FFFu + ((u >> 16) & 1u)) >> 16;
  return (short)r;
}

__device__ __forceinline__ unsigned ldA(const unsigned* p) {
  return __hip_atomic_load(p, __ATOMIC_RELAXED, __HIP_MEMORY_SCOPE_AGENT);
}
__device__ __forceinline__ void stA(unsigned* p, unsigned v) {
  __hip_atomic_store(p, v, __ATOMIC_RELAXED, __HIP_MEMORY_SCOPE_AGENT);
}

// ---------------- generic GEMM tile (carved smem) ----------------
template <int ATOMICST>
__device__ __forceinline__ void gemm_tile(
    char* smem,
    const float* __restrict__ A, int lda,
    const float* __restrict__ Bw, int ldb,
    const float* __restrict__ bias, const float* __restrict__ bias2,
    float* __restrict__ C, int ldc, int N, int m0, int n0,
    const int* __restrict__ ids, const float* __restrict__ emb)
{
  float (*As)[65] = (float (*)[65])smem;
  float (*Bs)[65] = (float (*)[65])(smem + 4160);
  const int tid = threadIdx.x;
  const int tx = tid & 15, ty = tid >> 4;
  float acc[4][4] = {};
  for (int k0 = 0; k0 < 512; k0 += 16) {
#pragma unroll
    for (int i = 0; i < 4; ++i) {
      int n = n0 + ty + 16 * i;
      float av = 0.f;
      if (n < N) {
        const float* ar = ids ? (emb + (long)ids[n] * 512) : (A + (long)n * lda);
        av = ar[k0 + tx];
      }
      As[tx][ty + 16 * i] = av;
      Bs[tx][ty + 16 * i] = Bw[(long)(m0 + ty + 16 * i) * ldb + k0 + tx];
    }
    __syncthreads();
#pragma unroll
    for (int kl = 0; kl < 16; ++kl) {
      float a[4], b[4];
#pragma unroll
      for (int i = 0; i < 4; ++i) a[i] = As[kl][ty * 4 + i];
#pragma unroll
      for (int j = 0; j < 4; ++j) b[j] = Bs[kl][tx * 4 + j];
#pragma unroll
      for (int i = 0; i < 4; ++i)
#pragma unroll
        for (int j = 0; j < 4; ++j) acc[i][j] += a[i] * b[j];
    }
    __syncthreads();
  }
#pragma unroll
  for (int i = 0; i < 4; ++i) {
    int n = n0 + ty * 4 + i;
    if (n >= N) continue;
#pragma unroll
    for (int j = 0; j < 4; ++j) {
      int m = m0 + tx * 4 + j;
      float v = acc[i][j];
      if (bias)  v += bias[m];
      if (bias2) v += bias2[m];
      if (ATOMICST)
        stA((unsigned*)C + (long)n * ldc + m, __float_as_uint(v));
      else
        C[(long)n * ldc + m] = v;
    }
  }
}

// ---------------- wdc tile ----------------
__device__ void wdc_tile(char* smem,
                         const float* __restrict__ jw1,
                         const float* __restrict__ fc_w,
                         float* __restrict__ wdc, int n0, int m0)
{
  float (*As)[65] = (float (*)[65])smem;
  float (*Bs)[65] = (float (*)[65])(smem + 4160);
  const int tid = threadIdx.x;
  const int tx = tid & 15, ty = tid >> 4;
  float acc[4][4] = {};
  for (int k0 = 0; k0 < 512; k0 += 16) {
#pragma unroll
    for (int i = 0; i < 4; ++i) {
      As[tx][ty + 16 * i] = jw1[(long)(n0 + ty + 16 * i) * 1024 + 512 + k0 + tx];
      Bs[ty][tx + 16 * i] = fc_w[(long)(k0 + ty) * 512 + m0 + tx + 16 * i];
    }
    __syncthreads();
#pragma unroll
    for (int kl = 0; kl < 16; ++kl) {
      float a[4], b[4];
#pragma unroll
      for (int i = 0; i < 4; ++i) a[i] = As[kl][ty * 4 + i];
#pragma unroll
      for (int j = 0; j < 4; ++j) b[j] = Bs[kl][tx * 4 + j];
#pragma unroll
      for (int i = 0; i < 4; ++i)
#pragma unroll
        for (int j = 0; j < 4; ++j) acc[i][j] += a[i] * b[j];
    }
    __syncthreads();
  }
#pragma unroll
  for (int i = 0; i < 4; ++i)
#pragma unroll
    for (int j = 0; j < 4; ++j)
      stA((unsigned*)wdc + (long)(n0 + ty * 4 + i) * 512 + m0 + tx * 4 + j,
          __float_as_uint(acc[i][j]));
}

// ---------------- dec tile (advisory flag + per-word NaN backstop) ----------
__device__ void dec_tile(char* smem,
                         const float* __restrict__ h1s, const float* __restrict__ wdc,
                         const float* __restrict__ jw1, const float* __restrict__ fc_b,
                         const float* __restrict__ jb1, float* __restrict__ decb,
                         const int* __restrict__ f1, int m0, int n0)
{
  float (*As)[65] = (float (*)[65])smem;
  float (*Bs)[65] = (float (*)[65])(smem + 4160);
  float* biasl = (float*)(smem + 8320);
  const int tid = threadIdx.x;
  const int tx = tid & 15, ty = tid >> 4;
  int u_hi = 0;
  for (int rr = 0; rr < 64; ++rr) {
    int r = n0 + rr;
    if (r < 400) { int u = r % Uc; u_hi = max(u_hi, u + 1); }
  }
  if (tid < 32)
    while ((int)ldA((const unsigned*)(f1 + tid * 16)) < u_hi)
      __builtin_amdgcn_s_sleep(8);
  if (tid < 64) {
    int m = m0 + tid;
    const float4* wp = (const float4*)(jw1 + (long)m * 1024 + 512);
    const float4* fb = (const float4*)fc_b;
    float bb = jb1[m];
#pragma unroll 8
    for (int d4 = 0; d4 < 128; ++d4) {
      float4 w = wp[d4], f = fb[d4];
      bb += w.x * f.x + w.y * f.y + w.z * f.z + w.w * f.w;
    }
    biasl[tid] = bb;
  }
  __syncthreads();
  const unsigned* h1u = (const unsigned*)h1s;
  const unsigned* wdu = (const unsigned*)wdc;
  float acc[4][4] = {};
  for (int k0 = 0; k0 < 512; k0 += 16) {
    unsigned uA[4], uB[4];
#pragma unroll
    for (int i = 0; i < 4; ++i) {
      int n = n0 + ty + 16 * i;
      uA[i] = (n < 400) ? ldA(h1u + (long)(n % Uc) * G4 + (n / Uc) * 512 + k0 + tx) : 0u;
      uB[i] = ldA(wdu + (long)(m0 + ty + 16 * i) * 512 + k0 + tx);
    }
#pragma unroll
    for (int i = 0; i < 4; ++i) {
      int n = n0 + ty + 16 * i;
      while (uA[i] == 0xFFFFFFFFu)
        uA[i] = ldA(h1u + (long)(n % Uc) * G4 + (n / Uc) * 512 + k0 + tx);
      while (uB[i] == 0xFFFFFFFFu)
        uB[i] = ldA(wdu + (long)(m0 + ty + 16 * i) * 512 + k0 + tx);
      As[tx][ty + 16 * i] = __uint_as_float(uA[i]);
      Bs[tx][ty + 16 * i] = __uint_as_float(uB[i]);
    }
    __syncthreads();
#pragma unroll
    for (int kl = 0; kl < 16; ++kl) {
      float a[4], b[4];
#pragma unroll
      for (int i = 0; i < 4; ++i) a[i] = As[kl][ty * 4 + i];
#pragma unroll
      for (int j = 0; j < 4; ++j) b[j] = Bs[kl][tx * 4 + j];
#pragma unroll
      for (int i = 0; i < 4; ++i)
#pragma unroll
        for (int j = 0; j < 4; ++j) acc[i][j] += a[i] * b[j];
    }
    __syncthreads();
  }
#pragma unroll
  for (int i = 0; i < 4; ++i) {
    int n = n0 + ty * 4 + i;
    if (n >= 400) continue;
#pragma unroll
    for (int j = 0; j < 4; ++j)
      stA((unsigned*)decb + (long)n * 512 + m0 + tx * 4 + j,
          __float_as_uint(acc[i][j] + biasl[tx * 4 + j]));
  }
}

// ---------------- LSTM recurrence (r10 protocol + ixp prefetch) -------------
// role 0..15 : layer 0, 32 units each. role 16..47: layer 1, 16 units each.
// fp16 weights in VGPRs (v_dot2_f32_f16); fp16-packed write-once NaN h slots;
// agent-scope exchange; each rec block owns its CU exclusively (84KB LDS).
__device__ void rec_path(
    char* smem, int role,
    const float* __restrict__ ixp0,
    const float* __restrict__ wih1, const float* __restrict__ whh0,
    const float* __restrict__ whh1,
    const float* __restrict__ bih1, const float* __restrict__ bhh1,
    unsigned* __restrict__ h0s16, unsigned* __restrict__ h1s16,
    float* __restrict__ h1s32,
    float* __restrict__ hO, float* __restrict__ cO, int* __restrict__ flags)
{
  unsigned* hl = (unsigned*)smem;            // 2048 words
  float4* red4 = (float4*)(smem + 8192);     // 512 float4
  const int tid = threadIdx.x;
  const bool isL1 = role >= 16;
  const int jb = role - 16;
  const int rg = tid & 15, ks = tid >> 4;
  const int lane = tid & 63, wv = tid >> 6;
  int* f1 = flags + 512;

  // fp16 weight preload: 8 rows x 32 k -> 128 VGPRs
  h2v wr[8][16];
#pragma unroll
  for (int r = 0; r < 8; ++r) {
    int lr = rg * 8 + r;
    const float* wsrc; int grow;
    if (!isL1) { int q = lr >> 5, uu = lr & 31; grow = q * 512 + role * 32 + uu; wsrc = whh0; }
    else {
      if (lr < 64) { int q = lr >> 4, uu = lr & 15; grow = q * 512 + jb * 16 + uu; wsrc = wih1; }
      else { int l2 = lr - 64; int q = l2 >> 4, uu = l2 & 15; grow = q * 512 + jb * 16 + uu; wsrc = whh1; }
    }
    const float* wp = wsrc + (long)grow * 512 + ks * 32;
#pragma unroll
    for (int jj = 0; jj < 16; ++jj) {
      h2v t; t[0] = (_Float16)wp[2 * jj]; t[1] = (_Float16)wp[2 * jj + 1];
      wr[r][jj] = t;
    }
  }

  const int npair = isL1 ? 8 : 16;
  const bool eact = tid < npair * 4;
  const int ep = tid >> 2, eb = tid & 3;
  float creg[2] = {0.f, 0.f};
  float bgate[2][4];
  if (isL1 && eact) {
#pragma unroll
    for (int o = 0; o < 2; ++o)
#pragma unroll
      for (int q = 0; q < 4; ++q) {
        int grow = q * 512 + jb * 16 + 2 * ep + o;
        bgate[o][q] = bih1[grow] + bhh1[grow];
      }
  }

  const unsigned* ixu = (const unsigned*)ixp0;
  const int hsrc = (isL1 && rg >= 8) ? 1 : 0;
  const float* redf = (const float*)red4;

  // ixp prefetch one step ahead (feed is dependency-free)
  unsigned ixn[8];
  const unsigned* ib0 = (!isL1 && eact)
      ? ixu + ((long)(eb * Uc) * G4 + role * 32 + 2 * ep) : nullptr;
  if (ib0) {
#pragma unroll
    for (int o = 0; o < 2; ++o)
#pragma unroll
      for (int q = 0; q < 4; ++q) ixn[o * 4 + q] = ldA(ib0 + o + q * 512);
  }

  for (int s = 0; s < Uc; ++s) {
    // ---- gather packed h (write-once NaN slots) ----
    unsigned ha[4] = {0u, 0u, 0u, 0u}, hb[4] = {0u, 0u, 0u, 0u};
    const unsigned* pa = nullptr; const unsigned* pb = nullptr;
    if (!isL1) { if (s > 0) pa = h0s16 + (long)(s - 1) * 1024 + tid * 4; }
    else {
      pa = h0s16 + (long)s * 1024 + tid * 4;
      if (s > 0) pb = h1s16 + (long)(s - 1) * 1024 + tid * 4;
    }
    if (pa) {
#pragma unroll
      for (int c = 0; c < 4; ++c) ha[c] = ldA(pa + c);
    }
    if (pb) {
#pragma unroll
      for (int c = 0; c < 4; ++c) hb[c] = ldA(pb + c);
    }

    // ---- consume prefetched ixp (retry rare stragglers) ----
    float ixv[2][4] = {};
    if (ib0) {
      const unsigned* ib = ib0 + (long)s * G4;
#pragma unroll
      for (int o = 0; o < 2; ++o)
#pragma unroll
        for (int q = 0; q < 4; ++q) {
          unsigned g = ixn[o * 4 + q];
          while (g == 0xFFFFFFFFu) { __builtin_amdgcn_s_sleep(1); g = ldA(ib + o + q * 512); }
          ixv[o][q] = __uint_as_float(g);
        }
    }

    // ---- per-word NaN backstop on h ----
    if (pa) {
#pragma unroll
      for (int c = 0; c < 4; ++c)
        while (ha[c] == 0xFFFFFFFFu) { __builtin_amdgcn_s_sleep(1); ha[c] = ldA(pa + c); }
    }
    if (pb) {
#pragma unroll
      for (int c = 0; c < 4; ++c)
        while (hb[c] == 0xFFFFFFFFu) { __builtin_amdgcn_s_sleep(1); hb[c] = ldA(pb + c); }
    }

    // ---- prefetch ixp for s+1 (in flight through the dot) ----
    if (ib0 && s + 1 < Uc) {
      const unsigned* ibn = ib0 + (long)(s + 1) * G4;
#pragma unroll
      for (int o = 0; o < 2; ++o)
#pragma unroll
        for (int q = 0; q < 4; ++q) ixn[o * 4 + q] = ldA(ibn + o + q * 512);
    }

    // ---- stage to LDS ----
    *(uint4*)&hl[tid * 4] = make_uint4(ha[0], ha[1], ha[2], ha[3]);
    if (isL1)
      *(uint4*)&hl[1024 + tid * 4] = make_uint4(hb[0], hb[1], hb[2], hb[3]);
    __syncthreads();

    // ---- dot via v_dot2_f32_f16 ----
    float acc[8][4] = {};
    const unsigned* hbase = &hl[hsrc * 1024 + ks * 16];
#pragma unroll
    for (int jw = 0; jw < 4; ++jw) {
      unsigned q[4][4];
#pragma unroll
      for (int b = 0; b < 4; ++b) {
        uint4 t = *(const uint4*)&hbase[b * 256 + jw * 4];
        q[b][0] = t.x; q[b][1] = t.y; q[b][2] = t.z; q[b][3] = t.w;
      }
#pragma unroll
      for (int r = 0; r < 8; ++r)
#pragma unroll
        for (int w = 0; w < 4; ++w) {
          h2v wv2 = wr[r][jw * 4 + w];
#pragma unroll
          for (int b = 0; b < 4; ++b)
            acc[r][b] = __builtin_amdgcn_fdot2(
                wv2, __builtin_bit_cast(h2v, q[b][w]), acc[r][b], false);
        }
    }
#pragma unroll
    for (int r = 0; r < 8; ++r)
#pragma unroll
      for (int b = 0; b < 4; ++b) {
        float v = acc[r][b];
        v += __shfl_xor(v, 16);
        v += __shfl_xor(v, 32);
        acc[r][b] = v;
      }
    if (lane < 16) {
#pragma unroll
      for (int r = 0; r < 8; ++r)
        red4[wv * 128 + lane * 8 + r] =
            make_float4(acc[r][0], acc[r][1], acc[r][2], acc[r][3]);
    }
    __syncthreads();

    // ---- epilogue: 2 units per thread, pack fp16 pair, write-once store ----
    if (eact) {
      float hn2[2], cn2[2];
#pragma unroll
      for (int o = 0; o < 2; ++o) {
        int uu = 2 * ep + o;
        float gv[4];
#pragma unroll
        for (int q = 0; q < 4; ++q) {
          int lrA = isL1 ? (q * 16 + uu) : (q * 32 + uu);
          float sv = 0.f;
#pragma unroll
          for (int w = 0; w < 4; ++w)
            sv += redf[(w * 128 + (lrA >> 3) * 8 + (lrA & 7)) * 4 + eb];
          if (isL1) {
            int lrB = 64 + q * 16 + uu;
#pragma unroll
            for (int w = 0; w < 4; ++w)
              sv += redf[(w * 128 + (lrB >> 3) * 8 + (lrB & 7)) * 4 + eb];
            sv += bgate[o][q];
          } else {
            sv += ixv[o][q];
          }
          gv[q] = sv;
        }
        float cn = fsig(gv[1]) * creg[o] + fsig(gv[0]) * ftanh(gv[2]);
        float hn = fsig(gv[3]) * ftanh(cn);
        creg[o] = cn;
        hn2[o] = hn; cn2[o] = cn;
      }
      int gu = (isL1 ? jb * 16 : role * 32) + 2 * ep;
      h2v hp; hp[0] = (_Float16)hn2[0]; hp[1] = (_Float16)hn2[1];
      unsigned pw = __builtin_bit_cast(unsigned, hp);
      stA((isL1 ? h1s16 : h0s16) + (long)s * 1024 + eb * 256 + (gu >> 1), pw);
      if (isL1) {
        unsigned* d32 = (unsigned*)h1s32 + (long)s * G4 + eb * 512 + gu;
        stA(d32, __float_as_uint(hn2[0]));
        stA(d32 + 1, __float_as_uint(hn2[1]));
      }
      if (s == Uc - 1) {
#pragma unroll
        for (int o = 0; o < 2; ++o) {
          hO[(isL1 ? G4 : 0) + eb * 512 + gu + o] = hn2[o];
          cO[(isL1 ? G4 : 0) + eb * 512 + gu + o] = cn2[o];
        }
      }
      if (isL1 && tid == 0) stA((unsigned*)(f1 + jb * 16), (unsigned)(s + 1));
    }
  }
}

// ---------------- fused launch: 256 blocks (1 per CU) ----------------
// blk 0..47: rec (exclusive CU). blk 48..255: workers sweep 600 tiles,
// 3 rounds static: t = (blk-48) + 208*k.  Tile map:
//   t 0..223 ixp | 224..287 wdc | 288..543 enc | 544..599 dec
__global__ __launch_bounds__(256, 1) void k_fused(
    const int* __restrict__ ids, const float* __restrict__ emb,
    const float* __restrict__ memory,
    const float* __restrict__ w_ih, const float* __restrict__ b_ih,
    const float* __restrict__ b_hh,
    const float* __restrict__ wih1, const float* __restrict__ whh0,
    const float* __restrict__ whh1,
    const float* __restrict__ bih1, const float* __restrict__ bhh1,
    const float* __restrict__ jw1, const float* __restrict__ jb1,
    const float* __restrict__ fc_w, const float* __restrict__ fc_b,
    float* __restrict__ ixp0, unsigned* __restrict__ h0s16,
    unsigned* __restrict__ h1s16, float* __restrict__ h1s32,
    float* __restrict__ wdc, float* __restrict__ decb, float* __restrict__ encb,
    float* __restrict__ hO, float* __restrict__ cO, int* __restrict__ flags)
{
  __shared__ __attribute__((aligned(16))) char smem[SMEM_BYTES];
  const int blk = blockIdx.x;
  if (blk < 48) {
    rec_path(smem, blk, ixp0, wih1, whh0, whh1, bih1, bhh1,
             h0s16, h1s16, h1s32, hO, cO, flags);
    return;
  }
  const int w = blk - 48;
  static const int nt_ord[7] = {0, 1, 3, 4, 2, 5, 6};
  for (int k = 0; k < 3; ++k) {
    int t = w + 208 * k;
    if (t >= 600) break;
    if (k) __syncthreads();
    if (t < 224) {
      gemm_tile<1>(smem, nullptr, 0, w_ih, 512, b_ih, b_hh,
                   ixp0, G4, Bc * Uc, (t % 32) * 64, nt_ord[t / 32] * 64, ids, emb);
    } else if (t < 288) {
      int g = t - 224;
      wdc_tile(smem, jw1, fc_w, wdc, (g & 7) * 64, (g >> 3) * 64);
    } else if (t < 544) {
      int g = t - 288;
      gemm_tile<0>(smem, memory, 512, jw1, 1024, nullptr, nullptr,
                   encb, 512, Bc * Tc, (g & 7) * 64, (g >> 3) * 64, nullptr, nullptr);
    } else {
      int g = t - 544;
      dec_tile(smem, h1s32, wdc, jw1, fc_b, jb1, decb, flags + 512,
               (g & 7) * 64, (g >> 3) * 64);
    }
  }
}

// ---------------- joint via bf16 MFMA (unchanged) ----------------
__global__ __launch_bounds__(256) void k_jmfma(
    const float* __restrict__ enc, const float* __restrict__ dec,
    const float* __restrict__ jw2, const float* __restrict__ jb2,
    float* __restrict__ out)
{
  __shared__ float el[512];
  __shared__ short th[112][136];
  const int tid = threadIdx.x;
  const int lane = tid & 63, wv = tid >> 6;
  const int bt = blockIdx.x;
  const int b = bt / Tc;
  const int v0 = wv * 16;
  const int vl = lane & 15, kg = lane >> 4;

  short8v breg[16];
#pragma unroll
  for (int ksx = 0; ksx < 16; ++ksx) {
    const float* wp = jw2 + (long)(v0 + vl) * 512 + ksx * 32 + kg * 8;
    float4 x0 = *(const float4*)wp;
    float4 x1 = *(const float4*)(wp + 4);
    short8v t;
    t[0] = f2bf(x0.x); t[1] = f2bf(x0.y); t[2] = f2bf(x0.z); t[3] = f2bf(x0.w);
    t[4] = f2bf(x1.x); t[5] = f2bf(x1.y); t[6] = f2bf(x1.z); t[7] = f2bf(x1.w);
    breg[ksx] = t;
  }
  const float jbv = jb2[v0 + vl];
  for (int i = tid; i < 512; i += 256) el[i] = enc[(long)bt * 512 + i];

  f32x4 acc[7];
#pragma unroll
  for (int ut = 0; ut < 7; ++ut) acc[ut] = (f32x4){0.f, 0.f, 0.f, 0.f};
  __syncthreads();

  const float* dec0 = dec + (long)b * Uc * 512;
  for (int kc = 0; kc < 4; ++kc) {
#pragma unroll 5
    for (int it = 0; it < 50; ++it) {
      int flat = it * 256 + tid;
      int u = flat >> 7, kk = flat & 127;
      float dv = dec0[(long)u * 512 + kc * 128 + kk];
      th[u][kk] = f2bf(ftanh(el[kc * 128 + kk] + dv));
    }
    __syncthreads();
#pragma unroll
    for (int ks4 = 0; ks4 < 4; ++ks4) {
      int ko = ks4 * 32 + kg * 8;
#pragma unroll
      for (int ut = 0; ut < 7; ++ut) {
        short8v a = *(const short8v*)&th[ut * 16 + vl][ko];
        acc[ut] = __builtin_amdgcn_mfma_f32_16x16x32_bf16(a, breg[kc * 4 + ks4],
                                                          acc[ut], 0, 0, 0);
      }
    }
    __syncthreads();
  }
#pragma unroll
  for (int ut = 0; ut < 7; ++ut) {
#pragma unroll
    for (int i = 0; i < 4; ++i) {
      int u = ut * 16 + kg * 4 + i;
      if (u < Uc)
        out[((long)bt * Uc + u) * 64 + v0 + vl] = acc[ut][i] + jbv;
    }
  }
}

extern "C" void kernel_launch(void* const* d_in, const int* in_sizes, int n_in,
                              void* d_out, int out_size, void* d_ws, size_t ws_size,
                              hipStream_t stream)
{
  const int*   ids    = (const int*)d_in[0];
  const float* memory = (const float*)d_in[1];
  const float* emb    = (const float*)d_in[2];
  const float* w_ih   = (const float*)d_in[3];
  const float* w_hh   = (const float*)d_in[4];
  const float* b_ih   = (const float*)d_in[5];
  const float* b_hh   = (const float*)d_in[6];
  const float* fc_w   = (const float*)d_in[7];
  const float* fc_b   = (const float*)d_in[8];
  const float* jw1    = (const float*)d_in[9];
  const float* jb1    = (const float*)d_in[10];
  const float* jw2    = (const float*)d_in[11];
  const float* jb2    = (const float*)d_in[12];
  float* out = (float*)d_out;

  float* wsf = (float*)d_ws;
  int*      flags = (int*)d_ws;                      // 4096 ints (f1 at +512)
  float*    ixp0  = wsf + 4096;                      // 819200
  unsigned* h0s16 = (unsigned*)(wsf + 823296);       // 102400 words
  unsigned* h1s16 = (unsigned*)(wsf + 925696);       // 102400 words
  float*    h1s32 = wsf + 1028096;                   // 204800
  float*    wdc   = wsf + 1232896;                   // 262144
  float*    decb  = wsf + 1495040;                   // 204800
  float*    encb  = wsf + 1699840;                   // 1024000

  float* hO = out + (long)Bc * Tc * Uc * Vc;
  float* cO = hO + 2 * Bc * 512;

  // flags = 0; NaN-init dataflow regions (ixp0,h0s16,h1s16,h1s32,wdc,decb)
  hipMemsetAsync(flags, 0, 4096 * 4, stream);
  hipMemsetAsync(ixp0, 0xFF, (size_t)(1699840 - 4096) * 4, stream);

  k_fused<<<256, 256, 0, stream>>>(ids, emb, memory,
                                   w_ih, b_ih, b_hh,
                                   w_ih + (long)G4 * 512,  // wih1
                                   w_hh,                   // whh0
                                   w_hh + (long)G4 * 512,  // whh1
                                   b_ih + G4, b_hh + G4,
                                   jw1, jb1, fc_w, fc_b,
                                   ixp0, h0s16, h1s16, h1s32, wdc, decb, encb,
                                   hO, cO, flags);

  k_jmfma<<<2000, 256, 0, stream>>>(encb, decb, jw2, jb2, out);
}